// Round 7
// baseline (43.213 us; speedup 1.0000x reference)
//
#include <hip/hip_runtime.h>
#include <stdint.h>

// R7: persistent waves + double-buffered LDS + counted vmcnt (T3/T4 at wave
// scope). Each wave processes UNITS_PER_WAVE units of 4 batches (2916 words
// = exactly 729 x 16B chunks = 12 DMA instrs). Two private LDS buffers:
// while unit i is computed+stored from buf[i&1], unit i+1's DMAs are in
// flight into buf[~i&1]; after storing, buf[i&1] is refilled with unit i+2.
// vmcnt retires IN ORDER, so "wait vmcnt(24)" == "oldest 12 (current
// unit's DMAs) done" while 12 next-unit DMAs + 12 prior stores stay live.
// No barriers: buffers are wave-private; wave lockstep + lgkmcnt order the
// LDS handoffs.
//
// Row logic (validated R1-R6, absmax 0): cand[w] = 9-bit candidate mask of
// cell w; every pair-mask (popcount 2) occurring exactly twice in the row
// erases its digits from all cells whose cand differs from it.

#define UNIT_BATCHES 4
#define UNIT_WORDS (UNIT_BATCHES * 729)  // 2916 words = 11664 B
#define UNIT_CHUNKS (UNIT_WORDS / 4)     // 729 16B chunks
#define UNITS_PER_WAVE 4
#define WAVES_PER_WG 2

typedef uint32_t u32x4 __attribute__((ext_vector_type(4)));
typedef const __attribute__((address_space(1))) uint32_t* gsrc_t;
typedef __attribute__((address_space(3))) uint32_t* lptr_t;

__device__ __forceinline__ void issue_dma(const uint32_t* gin, uint32_t* lbase,
                                          int lane) {
#pragma unroll
  for (int j = 0; j < 12; ++j) {
    int i = lane + j * 64;
    if (i < UNIT_CHUNKS) {
      __builtin_amdgcn_global_load_lds((gsrc_t)(gin + i * 4),
                                       (lptr_t)(lbase + i * 4), 16, 0, 0);
    }
  }
}

__device__ __forceinline__ void compute_unit(uint32_t* lbase, int lane) {
  if (lane < UNIT_BATCHES * 9) {
    const int bl = lane / 9;
    const int h = lane - bl * 9;
    const int rbase = bl * 729 + h * 9;

    uint32_t cand[9];
#pragma unroll
    for (int w = 0; w < 9; ++w) cand[w] = 0u;
#pragma unroll
    for (int d = 0; d < 9; ++d) {
#pragma unroll
      for (int w = 0; w < 9; ++w)
        cand[w] |= (lbase[rbase + d * 81 + w] ? 1u : 0u) << d;
    }

    uint32_t clearbits[9];
#pragma unroll
    for (int w = 0; w < 9; ++w) clearbits[w] = 0u;
#pragma unroll
    for (int w1 = 0; w1 < 9; ++w1) {
      uint32_t c1 = cand[w1];
      if (__popc(c1) != 2) continue;
      int cnt = 0;
#pragma unroll
      for (int w2 = 0; w2 < 9; ++w2) cnt += (cand[w2] == c1) ? 1 : 0;
      if (cnt == 2) {
#pragma unroll
        for (int w = 0; w < 9; ++w)
          if (cand[w] != c1) clearbits[w] |= c1;
      }
    }

#pragma unroll
    for (int d = 0; d < 9; ++d) {
#pragma unroll
      for (int w = 0; w < 9; ++w) {
        uint32_t k = (cand[w] & ~clearbits[w]) >> d;
        lbase[rbase + d * 81 + w] = (k & 1u) ? 0x3F800000u : 0u;
      }
    }
  }
}

__device__ __forceinline__ void store_unit(const uint32_t* lbase,
                                           uint32_t* gout, int lane) {
#pragma unroll
  for (int j = 0; j < 12; ++j) {
    int i = lane + j * 64;
    if (i < UNIT_CHUNKS) {
      u32x4 v = *(const u32x4*)(lbase + i * 4);
      *(u32x4*)(gout + i * 4) = v;
    }
  }
}

__global__ __launch_bounds__(WAVES_PER_WG * 64) void sudoku_kernel(
    const uint32_t* __restrict__ in, uint32_t* __restrict__ out) {
  __shared__ __align__(16) uint32_t lds[WAVES_PER_WG][2][UNIT_WORDS];
  const int lane = threadIdx.x & 63;
  const int wslot = threadIdx.x >> 6;
  const int wave_id = blockIdx.x * WAVES_PER_WG + wslot;
  const size_t base_unit = (size_t)wave_id * UNITS_PER_WAVE;

  uint32_t* buf0 = &lds[wslot][0][0];
  uint32_t* buf1 = &lds[wslot][1][0];

  // Prologue: fill both buffers (units 0 and 1).
  issue_dma(in + (base_unit + 0) * UNIT_WORDS, buf0, lane);
  issue_dma(in + (base_unit + 1) * UNIT_WORDS, buf1, lane);

#pragma unroll
  for (int u = 0; u < UNITS_PER_WAVE; ++u) {
    uint32_t* cur = (u & 1) ? buf1 : buf0;
    // Outstanding vmem (issue order): cur's 12 DMAs [oldest], then (u>=1)
    // 12 stores of unit u-1, then (u<=2) 12 DMAs of unit u+1. Wait for the
    // oldest 12 to retire (in-order) leaving the rest in flight.
    if (u == 0 || u == UNITS_PER_WAVE - 1)
      asm volatile("s_waitcnt vmcnt(12)" ::: "memory");
    else
      asm volatile("s_waitcnt vmcnt(24)" ::: "memory");

    compute_unit(cur, lane);
    store_unit(cur, out + (base_unit + u) * UNIT_WORDS, lane);

    if (u + 2 < UNITS_PER_WAVE) {
      // All of cur's ds_reads must retire before the DMA overwrites it
      // (ds uses lgkmcnt, DMA lands via vmcnt -- different queues).
      asm volatile("s_waitcnt lgkmcnt(0)" ::: "memory");
      issue_dma(in + (base_unit + u + 2) * UNIT_WORDS, cur, lane);
    }
  }
}

extern "C" void kernel_launch(void* const* d_in, const int* in_sizes, int n_in,
                              void* d_out, int out_size, void* d_ws, size_t ws_size,
                              hipStream_t stream) {
  const uint32_t* in = (const uint32_t*)d_in[0];  // mask, float32 binary
  uint32_t* out = (uint32_t*)d_out;               // float32 out, bit-patterns
  int B = in_sizes[0] / 729;                      // 32768
  int nunits = B / UNIT_BATCHES;                  // 8192
  int nwaves = nunits / UNITS_PER_WAVE;           // 2048
  int blocks = nwaves / WAVES_PER_WG;             // 1024
  sudoku_kernel<<<blocks, WAVES_PER_WG * 64, 0, stream>>>(in, out);
}

// Round 8
// 35.968 us; speedup vs baseline: 1.2014x; 1.2014x over previous
//
#include <hip/hip_runtime.h>
#include <stdint.h>

// R8 = R5 (best: 35.0 us) + non-temporal full-line stores.
//   Phase 1: 8 batches (5832 words, 22.8 KB) global->LDS via global_load_lds
//            16B DMA chunks, fully coalesced, no VGPR round-trip.
//   Phase 2: 72 threads = one per (batch,row): build 9-bit candidate masks
//            from LDS, naked-pair elimination, write 1.0f/0.0f patterns back
//            to the same (thread-private) LDS words.
//   Phase 3: coalesced dwordx4 LDS->global NON-TEMPORAL stores. Full 64B
//            lines per wave-quad (unlike R2's scattered 36B NT stores that
//            inflated WRITE_SIZE) -> stream to HBM, keep output OUT of L3
//            so the 95.6 MB input stays L3-resident across replays.
//
// Row logic (validated R1-R7, absmax 0): cand[w] = 9-bit candidate mask of
// cell w; every pair-mask (popcount 2) occurring exactly twice in the row
// erases its digits from all cells whose cand differs from it.

#define GBATCH 8
#define WORDS_PER_WG (GBATCH * 729)  // 5832 words = 23328 B
#define CHUNKS (WORDS_PER_WG / 4)    // 1458 16B chunks

typedef uint32_t u32x4 __attribute__((ext_vector_type(4)));
typedef const __attribute__((address_space(1))) uint32_t* gsrc_t;
typedef __attribute__((address_space(3))) uint32_t* lptr_t;

__global__ __launch_bounds__(256) void sudoku_kernel(
    const uint32_t* __restrict__ in, uint32_t* __restrict__ out) {
  __shared__ uint32_t lds[WORDS_PER_WG];
  const int g = blockIdx.x;
  const int t = threadIdx.x;
  const uint32_t* gin = in + (size_t)g * WORDS_PER_WG;

  // ---- Phase 1: global -> LDS, 16B DMA, coalesced ----
#pragma unroll
  for (int j = 0; j < 6; ++j) {
    int i = t + j * 256;
    if (i < CHUNKS) {
      __builtin_amdgcn_global_load_lds((gsrc_t)(gin + i * 4),
                                       (lptr_t)(&lds[i * 4]), 16, 0, 0);
    }
  }
  __syncthreads();  // drains vmcnt (LDS-DMA) before any LDS read

  // ---- Phase 2: per-row naked-pair logic ----
  if (t < GBATCH * 9) {
    const int bl = t / 9;
    const int h = t - bl * 9;
    const int rbase = bl * 729 + h * 9;

    uint32_t cand[9];
#pragma unroll
    for (int w = 0; w < 9; ++w) cand[w] = 0u;
#pragma unroll
    for (int d = 0; d < 9; ++d) {
#pragma unroll
      for (int w = 0; w < 9; ++w)
        cand[w] |= (lds[rbase + d * 81 + w] ? 1u : 0u) << d;
    }

    uint32_t clearbits[9];
#pragma unroll
    for (int w = 0; w < 9; ++w) clearbits[w] = 0u;
#pragma unroll
    for (int w1 = 0; w1 < 9; ++w1) {
      uint32_t c1 = cand[w1];
      if (__popc(c1) != 2) continue;
      int cnt = 0;
#pragma unroll
      for (int w2 = 0; w2 < 9; ++w2) cnt += (cand[w2] == c1) ? 1 : 0;
      if (cnt == 2) {
#pragma unroll
        for (int w = 0; w < 9; ++w)
          if (cand[w] != c1) clearbits[w] |= c1;
      }
    }

    uint32_t keep[9];
#pragma unroll
    for (int w = 0; w < 9; ++w) keep[w] = cand[w] & ~clearbits[w];

    // Write 1.0f/0.0f patterns back to the same (thread-private) words.
#pragma unroll
    for (int d = 0; d < 9; ++d) {
#pragma unroll
      for (int w = 0; w < 9; ++w)
        lds[rbase + d * 81 + w] =
            ((keep[w] >> d) & 1u) ? 0x3F800000u : 0u;
    }
  }
  __syncthreads();

  // ---- Phase 3: LDS -> global, dwordx4, coalesced, NON-TEMPORAL ----
  uint32_t* gout = out + (size_t)g * WORDS_PER_WG;
#pragma unroll
  for (int j = 0; j < 6; ++j) {
    int i = t + j * 256;
    if (i < CHUNKS) {
      u32x4 v = {lds[i * 4], lds[i * 4 + 1], lds[i * 4 + 2], lds[i * 4 + 3]};
      __builtin_nontemporal_store(v, (u32x4*)(gout + i * 4));
    }
  }
}

extern "C" void kernel_launch(void* const* d_in, const int* in_sizes, int n_in,
                              void* d_out, int out_size, void* d_ws, size_t ws_size,
                              hipStream_t stream) {
  const uint32_t* in = (const uint32_t*)d_in[0];  // mask, float32 binary
  uint32_t* out = (uint32_t*)d_out;               // float32 out, bit-patterns
  int B = in_sizes[0] / 729;
  int blocks = B / GBATCH;  // B = 32768 -> 4096 WGs
  sudoku_kernel<<<blocks, 256, 0, stream>>>(in, out);
}